// Round 8
// baseline (296.445 us; speedup 1.0000x reference)
//
#include <hip/hip_runtime.h>
#include <hip/hip_bf16.h>
#include <stdint.h>

typedef unsigned short u16;
typedef unsigned int u32;

typedef __attribute__((ext_vector_type(8))) __bf16 bf16x8;
typedef __attribute__((ext_vector_type(4))) _Float16 f16x4;
typedef __attribute__((ext_vector_type(4))) float f32x4;
typedef __attribute__((ext_vector_type(4))) u16 u16x4;
typedef __attribute__((ext_vector_type(8))) u16 u16x8;

#define DIM 1024
#define SEQ 4096
#define NTOK 8192   // b*n
#define NBH 16      // b*h
#define NSLOT 96    // per-head split-K slots: qt<32 -> 1 chunk, qt>=32 -> 2 chunks

// Legacy K=16 f16 MFMA (v_mfma_f32_16x16x16_f16, gfx950 ISA §10).
// NOTE: do NOT gate on __has_builtin — it returns 0 in the HIP host pass.
#define MFMA16X16F16 __builtin_amdgcn_mfma_f32_16x16x16f16

static __device__ __forceinline__ float bf2f(u16 u) {
    union { u32 u; float f; } c; c.u = ((u32)u) << 16; return c.f;
}
static __device__ __forceinline__ u16 f2bf(float f) {
    union { float f; u32 u; } c; c.f = f;
    u32 u = c.u;
    return (u16)((u + 0x7FFF + ((u >> 16) & 1)) >> 16);
}
static __device__ __forceinline__ u16 f2h(float f) {
    union { _Float16 h; u16 u; } c; c.h = (_Float16)f; return c.u;
}
static __device__ __forceinline__ f32x4 mfma_bf16(bf16x8 a, bf16x8 b, f32x4 c) {
    return __builtin_amdgcn_mfma_f32_16x16x32_bf16(a, b, c, 0, 0, 0);
}

typedef const __attribute__((address_space(1))) unsigned int* gptr_t;
typedef __attribute__((address_space(3))) unsigned int* lptr_t;

// ---------------- LayerNorm: one block per token row (fp32 in, bf16 out) ----
__global__ __launch_bounds__(256) void ln_kernel(const float* __restrict__ x,
                                                 const float* __restrict__ g,
                                                 const float* __restrict__ bta,
                                                 u16* __restrict__ xn) {
    int row = blockIdx.x;
    int tid = threadIdx.x;
    float4 v = ((const float4*)(x + (size_t)row * DIM))[tid];
    float f[4] = {v.x, v.y, v.z, v.w};
    float s = 0.f, s2 = 0.f;
#pragma unroll
    for (int i = 0; i < 4; i++) { s += f[i]; s2 += f[i] * f[i]; }
#pragma unroll
    for (int m = 1; m < 64; m <<= 1) { s += __shfl_xor(s, m); s2 += __shfl_xor(s2, m); }
    __shared__ float red[8];
    int w = tid >> 6;
    if ((tid & 63) == 0) { red[w * 2] = s; red[w * 2 + 1] = s2; }
    __syncthreads();
    s  = red[0] + red[2] + red[4] + red[6];
    s2 = red[1] + red[3] + red[5] + red[7];
    float mu = s * (1.f / DIM);
    float var = s2 * (1.f / DIM) - mu * mu;
    float rstd = rsqrtf(var + 1e-5f);
    u16 o[4];
#pragma unroll
    for (int i = 0; i < 4; i++) {
        int c = tid * 4 + i;
        o[i] = f2bf((f[i] - mu) * rstd * g[c] + bta[c]);
    }
    *(uint64_t*)(xn + (size_t)row * DIM + tid * 4) = *(uint64_t*)o;
}

// ---------------- transpose src[R][C] fp32 -> dst[C][R] bf16 ----------------
__global__ __launch_bounds__(256) void transpose_kernel(const float* __restrict__ src,
                                                        u16* __restrict__ dst,
                                                        int R, int C) {
    __shared__ float t[32][33];
    int lx = threadIdx.x & 31, ly = threadIdx.x >> 5;
    int c = blockIdx.x * 32 + lx;
#pragma unroll
    for (int i = 0; i < 32; i += 8)
        t[ly + i][lx] = src[(size_t)(blockIdx.y * 32 + ly + i) * C + c];
    __syncthreads();
    int rr = blockIdx.y * 32 + lx;
#pragma unroll
    for (int i = 0; i < 32; i += 8)
        dst[(size_t)(blockIdx.x * 32 + ly + i) * R + rr] = f2bf(t[lx][ly + i]);
}

// ---------------- 128x128 MFMA GEMM core (m97-style global_load_lds) -------
template <int K>
static __device__ __forceinline__ void gemm_core(const u16* __restrict__ A,
                                                 const u16* __restrict__ B,
                                                 int rowBase, int colBase,
                                                 u16* A_lds, u16* B_lds,
                                                 f32x4 acc[4][4]) {
    int tid = threadIdx.x;
    int lane = tid & 63;
    int l15 = lane & 15, q4 = lane >> 4;
    int w = tid >> 6;
    int wm = w >> 1, wn = w & 1;
#pragma unroll
    for (int mt = 0; mt < 4; mt++)
#pragma unroll
        for (int nt = 0; nt < 4; nt++) acc[mt][nt] = (f32x4){0.f, 0.f, 0.f, 0.f};

    char* Ab = (char*)A_lds;
    char* Bb = (char*)B_lds;

    for (int k0 = 0; k0 < K; k0 += 32) {
        __syncthreads();
#pragma unroll
        for (int i = 0; i < 2; i++) {
            int c = i * 256 + tid;
            int r = c >> 2;
            int piece = (c & 3) * 8;
            const u16* gA = A + (size_t)(rowBase + r) * K + k0 + piece;
            const u16* gB = B + (size_t)(colBase + r) * K + k0 + piece;
            unsigned ldsOff = (unsigned)(i * 4096 + w * 1024);  // wave-uniform
            __builtin_amdgcn_global_load_lds((gptr_t)gA, (lptr_t)(Ab + ldsOff), 16, 0, 0);
            __builtin_amdgcn_global_load_lds((gptr_t)gB, (lptr_t)(Bb + ldsOff), 16, 0, 0);
        }
        __syncthreads();
        bf16x8 a[4], b[4];
#pragma unroll
        for (int mt = 0; mt < 4; mt++)
            a[mt] = *(const bf16x8*)(A_lds + (wm * 64 + mt * 16 + l15) * 32 + q4 * 8);
#pragma unroll
        for (int nt = 0; nt < 4; nt++)
            b[nt] = *(const bf16x8*)(B_lds + (wn * 64 + nt * 16 + l15) * 32 + q4 * 8);
#pragma unroll
        for (int mt = 0; mt < 4; mt++)
#pragma unroll
            for (int nt = 0; nt < 4; nt++)
                acc[mt][nt] = mfma_bf16(a[mt], b[nt], acc[mt][nt]);
    }
}

// QKV GEMM: q pre-scaled; k bf16; v TRANSPOSED [bh][d][n] in **f16**
__global__ __launch_bounds__(256) void gemm_qkv_kernel(const u16* __restrict__ xn,
                                                       const u16* __restrict__ wT,
                                                       u16* __restrict__ qb,
                                                       u16* __restrict__ kb,
                                                       u16* __restrict__ vbT) {
    __shared__ u16 A_lds[128 * 32];
    __shared__ u16 B_lds[128 * 32];
    f32x4 acc[4][4];
    gemm_core<1024>(xn, wT, blockIdx.x * 128, blockIdx.y * 128, A_lds, B_lds, acc);
    int lane = threadIdx.x & 63;
    int w = threadIdx.x >> 6;
    int wm = w >> 1, wn = w & 1;
    const float SC = 0.125f * 1.44269504f;  // scale * log2(e), folded into q
#pragma unroll
    for (int mt = 0; mt < 4; mt++) {
#pragma unroll
        for (int nt = 0; nt < 4; nt++) {
#pragma unroll
            for (int r = 0; r < 4; r++) {
                int m = blockIdx.x * 128 + wm * 64 + mt * 16 + (lane >> 4) * 4 + r;
                int n = blockIdx.y * 128 + wn * 64 + nt * 16 + (lane & 15);
                int piece = n >> 9;
                int c = n & 511;
                int h = c >> 6;
                int d = c & 63;
                int bi = m >> 12;
                int nn = m & 4095;
                int bh = bi * 8 + h;
                float av = acc[mt][nt][r];
                if (piece == 0)      qb[((size_t)(bh * SEQ + nn) << 6) + d] = f2bf(av * SC);
                else if (piece == 1) kb[((size_t)(bh * SEQ + nn) << 6) + d] = f2bf(av);
                else                 vbT[((size_t)(bh * 64 + d) << 12) + nn] = f2h(av);
            }
        }
    }
}

// Out projection GEMM -> d_out fp32
__global__ __launch_bounds__(256) void gemm_out_kernel(const u16* __restrict__ aout,
                                                       const u16* __restrict__ wT,
                                                       float* __restrict__ out) {
    __shared__ u16 A_lds[128 * 32];
    __shared__ u16 B_lds[128 * 32];
    f32x4 acc[4][4];
    gemm_core<512>(aout, wT, blockIdx.x * 128, blockIdx.y * 128, A_lds, B_lds, acc);
    int lane = threadIdx.x & 63;
    int w = threadIdx.x >> 6;
    int wm = w >> 1, wn = w & 1;
#pragma unroll
    for (int mt = 0; mt < 4; mt++) {
#pragma unroll
        for (int nt = 0; nt < 4; nt++) {
#pragma unroll
            for (int r = 0; r < 4; r++) {
                int m = blockIdx.x * 128 + wm * 64 + mt * 16 + (lane >> 4) * 4 + r;
                int n = blockIdx.y * 128 + wn * 64 + nt * 16 + (lane & 15);
                out[(size_t)m * DIM + n] = acc[mt][nt][r];
            }
        }
    }
}

// ---------------- split-K causal flash attention, barrier-free K-loop ------
// S^T = K·Q^T (x32 bf16): C-frag(row=key=q4*4+r, col=q=l15) == B-operand layout
// of 16x16x16 f16 MFMA -> P feeds PV (O^T = V^T·P^T) directly from registers.
// Wave w owns keys {kt0*64 + w*16 + 64*i}; K/V fragments load straight from
// global in operand layout. No LDS, no __syncthreads in the loop.
__global__ __launch_bounds__(256) void attn_partial_kernel(const u16* __restrict__ qb,
                                                           const u16* __restrict__ kb,
                                                           const u16* __restrict__ vbT,
                                                           u16* __restrict__ part,
                                                           float* __restrict__ lpart) {
    __shared__ u16 redO[4 * 64 * 72];  // per-wave O^T partials (bf16), [w][q][d], pad 72
    __shared__ float redL[4 * 64];

    int idx = NBH * NSLOT - 1 - blockIdx.x;  // big chunks dispatch first
    int bh = idx / NSLOT;
    int s  = idx - bh * NSLOT;
    int qt, ci;
    if (s < 32) { qt = s; ci = 0; }
    else        { int t = s - 32; qt = 32 + (t >> 1); ci = t & 1; }
    int kt0 = ci * 32;
    int kt1 = min(kt0 + 31, qt);
    int nsteps = kt1 - kt0 + 1;

    int tid = threadIdx.x;
    int lane = tid & 63;
    int l15 = lane & 15, q4 = lane >> 4;
    int w = tid >> 6;

    const u16* Qb = qb + ((size_t)(bh * SEQ + qt * 64)) * 64;
    const u16* Kb = kb + (size_t)bh * SEQ * 64;
    const u16* Vb = vbT + (size_t)bh * 64 * SEQ;

    // Q B-fragments (x32): B[n=q=l15][k=d=dc*32+q4*8+j]
    bf16x8 Qf[4][2];
#pragma unroll
    for (int qtile = 0; qtile < 4; qtile++)
#pragma unroll
        for (int dc = 0; dc < 2; dc++)
            Qf[qtile][dc] = *(const bf16x8*)(Qb + (size_t)(qtile * 16 + l15) * 64 + dc * 32 + q4 * 8);

    f32x4 Oacc[4][4];  // [dtile][qtile] of O^T[d][q]
#pragma unroll
    for (int dt = 0; dt < 4; dt++)
#pragma unroll
        for (int qtile = 0; qtile < 4; qtile++) Oacc[dt][qtile] = (f32x4){0.f, 0.f, 0.f, 0.f};
    float l_acc[4] = {0.f, 0.f, 0.f, 0.f};

    int key0 = kt0 * 64 + w * 16;
    bf16x8 kf0, kf1, kn0, kn1;
    f16x4 vf[4], vn[4];
    kf0 = *(const bf16x8*)(Kb + (size_t)(key0 + l15) * 64 + q4 * 8);
    kf1 = *(const bf16x8*)(Kb + (size_t)(key0 + l15) * 64 + 32 + q4 * 8);
#pragma unroll
    for (int dt = 0; dt < 4; dt++)
        vf[dt] = *(const f16x4*)(Vb + (size_t)(dt * 16 + l15) * SEQ + key0 + q4 * 4);

    for (int i = 0; i < nsteps; i++) {
        int keyn = key0 + min(i + 1, nsteps - 1) * 64;  // register prefetch (clamped)
        kn0 = *(const bf16x8*)(Kb + (size_t)(keyn + l15) * 64 + q4 * 8);
        kn1 = *(const bf16x8*)(Kb + (size_t)(keyn + l15) * 64 + 32 + q4 * 8);
#pragma unroll
        for (int dt = 0; dt < 4; dt++)
            vn[dt] = *(const f16x4*)(Vb + (size_t)(dt * 16 + l15) * SEQ + keyn + q4 * 4);

        if (kt0 + i != qt) {
#pragma unroll
            for (int qtile = 0; qtile < 4; qtile++) {
                f32x4 z = (f32x4){0.f, 0.f, 0.f, 0.f};
                z = mfma_bf16(kf0, Qf[qtile][0], z);
                z = mfma_bf16(kf1, Qf[qtile][1], z);
                f16x4 pf;
#pragma unroll
                for (int r = 0; r < 4; r++) {
                    float pv = __builtin_amdgcn_exp2f(z[r]);
                    l_acc[qtile] += pv;
                    pf[r] = (_Float16)pv;
                }
#pragma unroll
                for (int dt = 0; dt < 4; dt++)
                    Oacc[dt][qtile] = MFMA16X16F16(vf[dt], pf, Oacc[dt][qtile], 0, 0, 0);
            }
        } else {  // diagonal 64-key group: mask key > query
#pragma unroll
            for (int qtile = 0; qtile < 4; qtile++) {
                f32x4 z = (f32x4){0.f, 0.f, 0.f, 0.f};
                z = mfma_bf16(kf0, Qf[qtile][0], z);
                z = mfma_bf16(kf1, Qf[qtile][1], z);
                f16x4 pf;
#pragma unroll
                for (int r = 0; r < 4; r++) {
                    float pv = (w * 16 + q4 * 4 + r <= qtile * 16 + l15)
                                   ? __builtin_amdgcn_exp2f(z[r]) : 0.f;
                    l_acc[qtile] += pv;
                    pf[r] = (_Float16)pv;
                }
#pragma unroll
                for (int dt = 0; dt < 4; dt++)
                    Oacc[dt][qtile] = MFMA16X16F16(vf[dt], pf, Oacc[dt][qtile], 0, 0, 0);
            }
        }
        kf0 = kn0; kf1 = kn1;
#pragma unroll
        for (int dt = 0; dt < 4; dt++) vf[dt] = vn[dt];
    }

    // cross-wave reduction: per-wave O^T -> LDS (bf16) -> sum -> partials out
#pragma unroll
    for (int qtile = 0; qtile < 4; qtile++) {
#pragma unroll
        for (int dt = 0; dt < 4; dt++) {
            u16 pk[4];
#pragma unroll
            for (int r = 0; r < 4; r++) pk[r] = f2bf(Oacc[dt][qtile][r]);
            *(uint64_t*)(redO + (size_t)(w * 64 + qtile * 16 + l15) * 72 + dt * 16 + q4 * 4) =
                *(uint64_t*)pk;
        }
        float l = l_acc[qtile];
        l += __shfl_xor(l, 16);
        l += __shfl_xor(l, 32);
        if (q4 == 0) redL[w * 64 + qtile * 16 + l15] = l;
    }
    __syncthreads();

    int q = tid >> 2;
    int ds = (tid & 3) * 16;
    float acc[16];
#pragma unroll
    for (int j = 0; j < 16; j++) acc[j] = 0.f;
    float ll = 0.f;
#pragma unroll
    for (int w2 = 0; w2 < 4; w2++) {
        const u16* pr = redO + (size_t)(w2 * 64 + q) * 72 + ds;
        u16x8 a0 = *(const u16x8*)pr;
        u16x8 a1 = *(const u16x8*)(pr + 8);
#pragma unroll
        for (int j = 0; j < 8; j++) { acc[j] += bf2f(a0[j]); acc[8 + j] += bf2f(a1[j]); }
        ll += redL[w2 * 64 + q];
    }
    u16 o[16];
#pragma unroll
    for (int j = 0; j < 16; j++) o[j] = f2bf(acc[j]);
    u16* po = part + (size_t)idx * 4096 + q * 64 + ds;
    *(u16x8*)po = *(u16x8*)o;
    *(u16x8*)(po + 8) = *(u16x8*)(o + 8);
    if ((tid & 3) == 0) lpart[(size_t)idx * 64 + q] = ll;
}

// combine partials -> aout bf16 [8192][512]
__global__ __launch_bounds__(256) void attn_combine_kernel(const u16* __restrict__ part,
                                                           const float* __restrict__ lpart,
                                                           u16* __restrict__ aout) {
    int bid = blockIdx.x;          // 16*64
    int bh = bid >> 6;
    int qt = bid & 63;
    int nc = 1 + (qt >> 5);
    int sb = bh * NSLOT + (qt < 32 ? qt : 32 + (qt - 32) * 2);

    int t = threadIdx.x;
    int q = t >> 2;
    int dg = (t & 3) * 16;

    float acc[16];
#pragma unroll
    for (int j = 0; j < 16; j++) acc[j] = 0.f;
    float ll = 0.f;
    for (int ci = 0; ci < nc; ci++) {
        const u16* pp = part + (size_t)(sb + ci) * 4096 + q * 64 + dg;
        u16x8 v0 = *(const u16x8*)pp;
        u16x8 v1 = *(const u16x8*)(pp + 8);
#pragma unroll
        for (int j = 0; j < 8; j++) { acc[j] += bf2f(v0[j]); acc[8 + j] += bf2f(v1[j]); }
        ll += lpart[(size_t)(sb + ci) * 64 + q];
    }
    float inv = 1.f / (ll + 1e-10f);
    int b = bh >> 3, h = bh & 7;
    size_t row = (size_t)(b * SEQ + qt * 64 + q);
    u16 o[16];
#pragma unroll
    for (int j = 0; j < 16; j++) o[j] = f2bf(acc[j] * inv);
    u16* dst = aout + row * 512 + h * 64 + dg;
    *(u16x8*)dst = *(u16x8*)o;
    *(u16x8*)(dst + 8) = *(u16x8*)(o + 8);
}

extern "C" void kernel_launch(void* const* d_in, const int* in_sizes, int n_in,
                              void* d_out, int out_size, void* d_ws, size_t ws_size,
                              hipStream_t stream) {
    const float* x    = (const float*)d_in[0];
    const float* g    = (const float*)d_in[1];
    const float* bta  = (const float*)d_in[2];
    const float* wqkv = (const float*)d_in[3];
    const float* wout = (const float*)d_in[4];
    float* out = (float*)d_out;

    char* ws = (char*)d_ws;
    size_t off = 0;
    auto alloc = [&](size_t bytes) {
        void* p = ws + off;
        off += (bytes + 255) & ~(size_t)255;
        return p;
    };
    // Footprint <= 46.1 MB (round-5's 76 MB overran d_ws; round-4's 54.6 known-good).
    u16* xn    = (u16*)alloc((size_t)NTOK * DIM * 2);       // 16.78 MB; dead after gemm_qkv
    u16* wqkvT = (u16*)alloc((size_t)1536 * 1024 * 2);      //  3.15 MB
    u16* woutT = (u16*)alloc((size_t)1024 * 512 * 2);       //  1.05 MB
    u16* qb    = (u16*)alloc((size_t)NBH * SEQ * 64 * 2);   //  8.39 MB; dead after attn_partial
    u16* kb    = (u16*)alloc((size_t)NBH * SEQ * 64 * 2);   //  8.39 MB
    u16* vbT   = (u16*)alloc((size_t)NBH * SEQ * 64 * 2);   //  8.39 MB (f16)
    // Aliases (lifetimes disjoint by stream order, valid on every replay):
    u16* part  = xn;
    float* lpart = (float*)(xn + (size_t)NBH * NSLOT * 4096);
    u16* aout  = qb;

    ln_kernel<<<NTOK, 256, 0, stream>>>(x, g, bta, xn);
    transpose_kernel<<<dim3(1536 / 32, 1024 / 32), 256, 0, stream>>>(wqkv, wqkvT, 1024, 1536);
    transpose_kernel<<<dim3(1024 / 32, 512 / 32), 256, 0, stream>>>(wout, woutT, 512, 1024);
    gemm_qkv_kernel<<<dim3(64, 12), 256, 0, stream>>>(xn, wqkvT, qb, kb, vbT);
    attn_partial_kernel<<<NBH * NSLOT, 256, 0, stream>>>(qb, kb, vbT, part, lpart);
    attn_combine_kernel<<<NBH * 64, 256, 0, stream>>>(part, lpart, aout);
    gemm_out_kernel<<<dim3(64, 8), 256, 0, stream>>>(aout, woutT, out);
}

// Round 9
// 261.091 us; speedup vs baseline: 1.1354x; 1.1354x over previous
//
#include <hip/hip_runtime.h>
#include <hip/hip_bf16.h>
#include <stdint.h>

typedef unsigned short u16;
typedef unsigned int u32;

typedef __attribute__((ext_vector_type(8))) __bf16 bf16x8;
typedef __attribute__((ext_vector_type(4))) _Float16 f16x4;
typedef __attribute__((ext_vector_type(4))) float f32x4;
typedef __attribute__((ext_vector_type(8))) u16 u16x8;

#define DIM 1024
#define SEQ 4096
#define NTOK 8192   // b*n
#define NBH 16      // b*h
#define NSLOT 96    // per-head split-K slots: qt<32 -> 1 chunk, qt>=32 -> 2 chunks
#define ASTR 72     // 64 + 8 pad (144 B rows)

// Legacy K=16 f16 MFMA (v_mfma_f32_16x16x16_f16). No __has_builtin gate (host pass).
#define MFMA16X16F16 __builtin_amdgcn_mfma_f32_16x16x16f16

static __device__ __forceinline__ float bf2f(u16 u) {
    union { u32 u; float f; } c; c.u = ((u32)u) << 16; return c.f;
}
static __device__ __forceinline__ u16 f2bf(float f) {
    union { float f; u32 u; } c; c.f = f;
    u32 u = c.u;
    return (u16)((u + 0x7FFF + ((u >> 16) & 1)) >> 16);
}
static __device__ __forceinline__ u16 f2h(float f) {
    union { _Float16 h; u16 u; } c; c.h = (_Float16)f; return c.u;
}
static __device__ __forceinline__ f32x4 mfma_bf16(bf16x8 a, bf16x8 b, f32x4 c) {
    return __builtin_amdgcn_mfma_f32_16x16x32_bf16(a, b, c, 0, 0, 0);
}

typedef const __attribute__((address_space(1))) unsigned int* gptr_t;
typedef __attribute__((address_space(3))) unsigned int* lptr_t;

// ---------------- LayerNorm: one block per token row (fp32 in, bf16 out) ----
__global__ __launch_bounds__(256) void ln_kernel(const float* __restrict__ x,
                                                 const float* __restrict__ g,
                                                 const float* __restrict__ bta,
                                                 u16* __restrict__ xn) {
    int row = blockIdx.x;
    int tid = threadIdx.x;
    float4 v = ((const float4*)(x + (size_t)row * DIM))[tid];
    float f[4] = {v.x, v.y, v.z, v.w};
    float s = 0.f, s2 = 0.f;
#pragma unroll
    for (int i = 0; i < 4; i++) { s += f[i]; s2 += f[i] * f[i]; }
#pragma unroll
    for (int m = 1; m < 64; m <<= 1) { s += __shfl_xor(s, m); s2 += __shfl_xor(s2, m); }
    __shared__ float red[8];
    int w = tid >> 6;
    if ((tid & 63) == 0) { red[w * 2] = s; red[w * 2 + 1] = s2; }
    __syncthreads();
    s  = red[0] + red[2] + red[4] + red[6];
    s2 = red[1] + red[3] + red[5] + red[7];
    float mu = s * (1.f / DIM);
    float var = s2 * (1.f / DIM) - mu * mu;
    float rstd = rsqrtf(var + 1e-5f);
    u16 o[4];
#pragma unroll
    for (int i = 0; i < 4; i++) {
        int c = tid * 4 + i;
        o[i] = f2bf((f[i] - mu) * rstd * g[c] + bta[c]);
    }
    *(uint64_t*)(xn + (size_t)row * DIM + tid * 4) = *(uint64_t*)o;
}

// ---------------- transpose src[R][C] fp32 -> dst[C][R] bf16 ----------------
__global__ __launch_bounds__(256) void transpose_kernel(const float* __restrict__ src,
                                                        u16* __restrict__ dst,
                                                        int R, int C) {
    __shared__ float t[32][33];
    int lx = threadIdx.x & 31, ly = threadIdx.x >> 5;
    int c = blockIdx.x * 32 + lx;
#pragma unroll
    for (int i = 0; i < 32; i += 8)
        t[ly + i][lx] = src[(size_t)(blockIdx.y * 32 + ly + i) * C + c];
    __syncthreads();
    int rr = blockIdx.y * 32 + lx;
#pragma unroll
    for (int i = 0; i < 32; i += 8)
        dst[(size_t)(blockIdx.x * 32 + ly + i) * R + rr] = f2bf(t[lx][ly + i]);
}

// ---------------- 128x128 MFMA GEMM core (m97-style global_load_lds) -------
template <int K>
static __device__ __forceinline__ void gemm_core(const u16* __restrict__ A,
                                                 const u16* __restrict__ B,
                                                 int rowBase, int colBase,
                                                 u16* A_lds, u16* B_lds,
                                                 f32x4 acc[4][4]) {
    int tid = threadIdx.x;
    int lane = tid & 63;
    int l15 = lane & 15, q4 = lane >> 4;
    int w = tid >> 6;
    int wm = w >> 1, wn = w & 1;
#pragma unroll
    for (int mt = 0; mt < 4; mt++)
#pragma unroll
        for (int nt = 0; nt < 4; nt++) acc[mt][nt] = (f32x4){0.f, 0.f, 0.f, 0.f};

    char* Ab = (char*)A_lds;
    char* Bb = (char*)B_lds;

    for (int k0 = 0; k0 < K; k0 += 32) {
        __syncthreads();
#pragma unroll
        for (int i = 0; i < 2; i++) {
            int c = i * 256 + tid;
            int r = c >> 2;
            int piece = (c & 3) * 8;
            const u16* gA = A + (size_t)(rowBase + r) * K + k0 + piece;
            const u16* gB = B + (size_t)(colBase + r) * K + k0 + piece;
            unsigned ldsOff = (unsigned)(i * 4096 + w * 1024);  // wave-uniform
            __builtin_amdgcn_global_load_lds((gptr_t)gA, (lptr_t)(Ab + ldsOff), 16, 0, 0);
            __builtin_amdgcn_global_load_lds((gptr_t)gB, (lptr_t)(Bb + ldsOff), 16, 0, 0);
        }
        __syncthreads();
        bf16x8 a[4], b[4];
#pragma unroll
        for (int mt = 0; mt < 4; mt++)
            a[mt] = *(const bf16x8*)(A_lds + (wm * 64 + mt * 16 + l15) * 32 + q4 * 8);
#pragma unroll
        for (int nt = 0; nt < 4; nt++)
            b[nt] = *(const bf16x8*)(B_lds + (wn * 64 + nt * 16 + l15) * 32 + q4 * 8);
#pragma unroll
        for (int mt = 0; mt < 4; mt++)
#pragma unroll
            for (int nt = 0; nt < 4; nt++)
                acc[mt][nt] = mfma_bf16(a[mt], b[nt], acc[mt][nt]);
    }
}

// QKV GEMM: q pre-scaled; k bf16; v TRANSPOSED [bh][d][n] in f16
__global__ __launch_bounds__(256) void gemm_qkv_kernel(const u16* __restrict__ xn,
                                                       const u16* __restrict__ wT,
                                                       u16* __restrict__ qb,
                                                       u16* __restrict__ kb,
                                                       u16* __restrict__ vbT) {
    __shared__ u16 A_lds[128 * 32];
    __shared__ u16 B_lds[128 * 32];
    f32x4 acc[4][4];
    gemm_core<1024>(xn, wT, blockIdx.x * 128, blockIdx.y * 128, A_lds, B_lds, acc);
    int lane = threadIdx.x & 63;
    int w = threadIdx.x >> 6;
    int wm = w >> 1, wn = w & 1;
    const float SC = 0.125f * 1.44269504f;  // scale * log2(e), folded into q
#pragma unroll
    for (int mt = 0; mt < 4; mt++) {
#pragma unroll
        for (int nt = 0; nt < 4; nt++) {
#pragma unroll
            for (int r = 0; r < 4; r++) {
                int m = blockIdx.x * 128 + wm * 64 + mt * 16 + (lane >> 4) * 4 + r;
                int n = blockIdx.y * 128 + wn * 64 + nt * 16 + (lane & 15);
                int piece = n >> 9;
                int c = n & 511;
                int h = c >> 6;
                int d = c & 63;
                int bi = m >> 12;
                int nn = m & 4095;
                int bh = bi * 8 + h;
                float av = acc[mt][nt][r];
                if (piece == 0)      qb[((size_t)(bh * SEQ + nn) << 6) + d] = f2bf(av * SC);
                else if (piece == 1) kb[((size_t)(bh * SEQ + nn) << 6) + d] = f2bf(av);
                else                 vbT[((size_t)(bh * 64 + d) << 12) + nn] = f2h(av);
            }
        }
    }
}

// Out projection GEMM -> d_out fp32
__global__ __launch_bounds__(256) void gemm_out_kernel(const u16* __restrict__ aout,
                                                       const u16* __restrict__ wT,
                                                       float* __restrict__ out) {
    __shared__ u16 A_lds[128 * 32];
    __shared__ u16 B_lds[128 * 32];
    f32x4 acc[4][4];
    gemm_core<512>(aout, wT, blockIdx.x * 128, blockIdx.y * 128, A_lds, B_lds, acc);
    int lane = threadIdx.x & 63;
    int w = threadIdx.x >> 6;
    int wm = w >> 1, wn = w & 1;
#pragma unroll
    for (int mt = 0; mt < 4; mt++) {
#pragma unroll
        for (int nt = 0; nt < 4; nt++) {
#pragma unroll
            for (int r = 0; r < 4; r++) {
                int m = blockIdx.x * 128 + wm * 64 + mt * 16 + (lane >> 4) * 4 + r;
                int n = blockIdx.y * 128 + wn * 64 + nt * 16 + (lane & 15);
                out[(size_t)m * DIM + n] = acc[mt][nt][r];
            }
        }
    }
}

// ---------------- split-K causal flash attention: hybrid -------------------
// LDS-staged K/V^T (latency hiding, round-6 style) + register P (round-8
// S^T=K·Q^T trick: S^T C-frag == PV B-operand layout). Wave w owns key-slice
// w*16 of each 64-key tile and all 64 queries; cross-wave O reduction at end
// into redO which ALIASES the Q/K/VT staging region (epilogue-only, barriers).
__global__ __launch_bounds__(256) void attn_partial_kernel(const u16* __restrict__ qb,
                                                           const u16* __restrict__ kb,
                                                           const u16* __restrict__ vbT,
                                                           u16* __restrict__ part,
                                                           float* __restrict__ lpart) {
    __shared__ u16 smem[4 * 64 * ASTR];  // loop: Q|K|VT (3*9216 B); epilogue: redO (36864 B)
    __shared__ float redL[256];
    u16* Q_lds  = smem;
    u16* K_lds  = smem + 64 * ASTR;
    u16* VT_lds = smem + 2 * 64 * ASTR;
    u16* redO   = smem;

    int idx = NBH * NSLOT - 1 - blockIdx.x;  // big chunks dispatch first
    int bh = idx / NSLOT;
    int s  = idx - bh * NSLOT;
    int qt, ci;
    if (s < 32) { qt = s; ci = 0; }
    else        { int t = s - 32; qt = 32 + (t >> 1); ci = t & 1; }
    int kt0 = ci * 32;
    int kt1 = min(kt0 + 31, qt);
    int nsteps = kt1 - kt0 + 1;

    int tid = threadIdx.x;
    int lane = tid & 63;
    int l15 = lane & 15, q4 = lane >> 4;
    int w = tid >> 6;

    const u16* Qb = qb + ((size_t)(bh * SEQ + qt * 64)) * 64;
    const u16* Kb = kb + (size_t)bh * SEQ * 64;
    const u16* Vb = vbT + (size_t)bh * 64 * SEQ;

    int c0 = tid, c1 = tid + 256;
    int r0 = c0 >> 3, kc0 = (c0 & 7) * 8;
    int r1 = c1 >> 3, kc1 = (c1 & 7) * 8;

    // stage Q (read under the loop's pre-compute barrier)
    *(u16x8*)(Q_lds + r0 * ASTR + kc0) = *(const u16x8*)(Qb + r0 * 64 + kc0);
    *(u16x8*)(Q_lds + r1 * ASTR + kc1) = *(const u16x8*)(Qb + r1 * 64 + kc1);

    // prefetch first K/V tile into registers
    u16x8 krA0 = *(const u16x8*)(Kb + (size_t)(kt0 * 64 + r0) * 64 + kc0);
    u16x8 krA1 = *(const u16x8*)(Kb + (size_t)(kt0 * 64 + r1) * 64 + kc1);
    u16x8 vrA0 = *(const u16x8*)(Vb + (size_t)r0 * SEQ + kt0 * 64 + kc0);
    u16x8 vrA1 = *(const u16x8*)(Vb + (size_t)r1 * SEQ + kt0 * 64 + kc1);

    f32x4 Oacc[4][4];  // [dtile][qtile] of O^T[d][q]
#pragma unroll
    for (int dt = 0; dt < 4; dt++)
#pragma unroll
        for (int qtile = 0; qtile < 4; qtile++) Oacc[dt][qtile] = (f32x4){0.f, 0.f, 0.f, 0.f};
    float l_acc[4] = {0.f, 0.f, 0.f, 0.f};

    for (int i = 0; i < nsteps; i++) {
        __syncthreads();  // previous compute's LDS reads done
        *(u16x8*)(K_lds + r0 * ASTR + kc0) = krA0;
        *(u16x8*)(K_lds + r1 * ASTR + kc1) = krA1;
        *(u16x8*)(VT_lds + r0 * ASTR + kc0) = vrA0;
        *(u16x8*)(VT_lds + r1 * ASTR + kc1) = vrA1;
        int kn = kt0 + min(i + 1, nsteps - 1);  // next tile, in flight across barrier
        krA0 = *(const u16x8*)(Kb + (size_t)(kn * 64 + r0) * 64 + kc0);
        krA1 = *(const u16x8*)(Kb + (size_t)(kn * 64 + r1) * 64 + kc1);
        vrA0 = *(const u16x8*)(Vb + (size_t)r0 * SEQ + kn * 64 + kc0);
        vrA1 = *(const u16x8*)(Vb + (size_t)r1 * SEQ + kn * 64 + kc1);
        __syncthreads();

        // wave w's K-slice fragments (A-operand of S^T = K·Q^T)
        bf16x8 kf0 = *(const bf16x8*)(K_lds + (w * 16 + l15) * ASTR + q4 * 8);
        bf16x8 kf1 = *(const bf16x8*)(K_lds + (w * 16 + l15) * ASTR + 32 + q4 * 8);
        f16x4 vf[4];
#pragma unroll
        for (int dt = 0; dt < 4; dt++)
            vf[dt] = *(const f16x4*)(VT_lds + (dt * 16 + l15) * ASTR + w * 16 + q4 * 4);

        if (kt0 + i != qt) {
#pragma unroll
            for (int qtile = 0; qtile < 4; qtile++) {
                bf16x8 qf0 = *(const bf16x8*)(Q_lds + (qtile * 16 + l15) * ASTR + q4 * 8);
                bf16x8 qf1 = *(const bf16x8*)(Q_lds + (qtile * 16 + l15) * ASTR + 32 + q4 * 8);
                f32x4 z = (f32x4){0.f, 0.f, 0.f, 0.f};
                z = mfma_bf16(kf0, qf0, z);
                z = mfma_bf16(kf1, qf1, z);
                f16x4 pf;
#pragma unroll
                for (int r = 0; r < 4; r++) {
                    float pv = __builtin_amdgcn_exp2f(z[r]);
                    l_acc[qtile] += pv;
                    pf[r] = (_Float16)pv;
                }
#pragma unroll
                for (int dt = 0; dt < 4; dt++)
                    Oacc[dt][qtile] = MFMA16X16F16(vf[dt], pf, Oacc[dt][qtile], 0, 0, 0);
            }
        } else {  // diagonal 64-key tile: mask key > query
#pragma unroll
            for (int qtile = 0; qtile < 4; qtile++) {
                bf16x8 qf0 = *(const bf16x8*)(Q_lds + (qtile * 16 + l15) * ASTR + q4 * 8);
                bf16x8 qf1 = *(const bf16x8*)(Q_lds + (qtile * 16 + l15) * ASTR + 32 + q4 * 8);
                f32x4 z = (f32x4){0.f, 0.f, 0.f, 0.f};
                z = mfma_bf16(kf0, qf0, z);
                z = mfma_bf16(kf1, qf1, z);
                f16x4 pf;
#pragma unroll
                for (int r = 0; r < 4; r++) {
                    float pv = (w * 16 + q4 * 4 + r <= qtile * 16 + l15)
                                   ? __builtin_amdgcn_exp2f(z[r]) : 0.f;
                    l_acc[qtile] += pv;
                    pf[r] = (_Float16)pv;
                }
#pragma unroll
                for (int dt = 0; dt < 4; dt++)
                    Oacc[dt][qtile] = MFMA16X16F16(vf[dt], pf, Oacc[dt][qtile], 0, 0, 0);
            }
        }
    }

    __syncthreads();  // all loop LDS reads done before redO overwrites Q/K/VT
#pragma unroll
    for (int qtile = 0; qtile < 4; qtile++) {
#pragma unroll
        for (int dt = 0; dt < 4; dt++) {
            u16 pk[4];
#pragma unroll
            for (int r = 0; r < 4; r++) pk[r] = f2bf(Oacc[dt][qtile][r]);
            *(uint64_t*)(redO + (size_t)(w * 64 + qtile * 16 + l15) * ASTR + dt * 16 + q4 * 4) =
                *(uint64_t*)pk;
        }
        float l = l_acc[qtile];
        l += __shfl_xor(l, 16);
        l += __shfl_xor(l, 32);
        if (q4 == 0) redL[w * 64 + qtile * 16 + l15] = l;
    }
    __syncthreads();

    int q = tid >> 2;
    int ds = (tid & 3) * 16;
    float acc[16];
#pragma unroll
    for (int j = 0; j < 16; j++) acc[j] = 0.f;
    float ll = 0.f;
#pragma unroll
    for (int w2 = 0; w2 < 4; w2++) {
        const u16* pr = redO + (size_t)(w2 * 64 + q) * ASTR + ds;
        u16x8 a0 = *(const u16x8*)pr;
        u16x8 a1 = *(const u16x8*)(pr + 8);
#pragma unroll
        for (int j = 0; j < 8; j++) { acc[j] += bf2f(a0[j]); acc[8 + j] += bf2f(a1[j]); }
        ll += redL[w2 * 64 + q];
    }
    u16 o[16];
#pragma unroll
    for (int j = 0; j < 16; j++) o[j] = f2bf(acc[j]);
    u16* po = part + (size_t)idx * 4096 + q * 64 + ds;
    *(u16x8*)po = *(u16x8*)o;
    *(u16x8*)(po + 8) = *(u16x8*)(o + 8);
    if ((tid & 3) == 0) lpart[(size_t)idx * 64 + q] = ll;
}

// combine partials -> aout bf16 [8192][512]
__global__ __launch_bounds__(256) void attn_combine_kernel(const u16* __restrict__ part,
                                                           const float* __restrict__ lpart,
                                                           u16* __restrict__ aout) {
    int bid = blockIdx.x;          // 16*64
    int bh = bid >> 6;
    int qt = bid & 63;
    int nc = 1 + (qt >> 5);
    int sb = bh * NSLOT + (qt < 32 ? qt : 32 + (qt - 32) * 2);

    int t = threadIdx.x;
    int q = t >> 2;
    int dg = (t & 3) * 16;

    float acc[16];
#pragma unroll
    for (int j = 0; j < 16; j++) acc[j] = 0.f;
    float ll = 0.f;
    for (int ci = 0; ci < nc; ci++) {
        const u16* pp = part + (size_t)(sb + ci) * 4096 + q * 64 + dg;
        u16x8 v0 = *(const u16x8*)pp;
        u16x8 v1 = *(const u16x8*)(pp + 8);
#pragma unroll
        for (int j = 0; j < 8; j++) { acc[j] += bf2f(v0[j]); acc[8 + j] += bf2f(v1[j]); }
        ll += lpart[(size_t)(sb + ci) * 64 + q];
    }
    float inv = 1.f / (ll + 1e-10f);
    int b = bh >> 3, h = bh & 7;
    size_t row = (size_t)(b * SEQ + qt * 64 + q);
    u16 o[16];
#pragma unroll
    for (int j = 0; j < 16; j++) o[j] = f2bf(acc[j] * inv);
    u16* dst = aout + row * 512 + h * 64 + dg;
    *(u16x8*)dst = *(u16x8*)o;
    *(u16x8*)(dst + 8) = *(u16x8*)(o + 8);
}

extern "C" void kernel_launch(void* const* d_in, const int* in_sizes, int n_in,
                              void* d_out, int out_size, void* d_ws, size_t ws_size,
                              hipStream_t stream) {
    const float* x    = (const float*)d_in[0];
    const float* g    = (const float*)d_in[1];
    const float* bta  = (const float*)d_in[2];
    const float* wqkv = (const float*)d_in[3];
    const float* wout = (const float*)d_in[4];
    float* out = (float*)d_out;

    char* ws = (char*)d_ws;
    size_t off = 0;
    auto alloc = [&](size_t bytes) {
        void* p = ws + off;
        off += (bytes + 255) & ~(size_t)255;
        return p;
    };
    // Footprint <= 46.1 MB (round-5's 76 MB overran d_ws; round-4's 54.6 known-good).
    u16* xn    = (u16*)alloc((size_t)NTOK * DIM * 2);       // 16.78 MB; dead after gemm_qkv
    u16* wqkvT = (u16*)alloc((size_t)1536 * 1024 * 2);      //  3.15 MB
    u16* woutT = (u16*)alloc((size_t)1024 * 512 * 2);       //  1.05 MB
    u16* qb    = (u16*)alloc((size_t)NBH * SEQ * 64 * 2);   //  8.39 MB; dead after attn_partial
    u16* kb    = (u16*)alloc((size_t)NBH * SEQ * 64 * 2);   //  8.39 MB
    u16* vbT   = (u16*)alloc((size_t)NBH * SEQ * 64 * 2);   //  8.39 MB (f16)
    // Aliases (lifetimes disjoint by stream order, valid on every replay):
    u16* part  = xn;
    float* lpart = (float*)(xn + (size_t)NBH * NSLOT * 4096);
    u16* aout  = qb;

    ln_kernel<<<NTOK, 256, 0, stream>>>(x, g, bta, xn);
    transpose_kernel<<<dim3(1536 / 32, 1024 / 32), 256, 0, stream>>>(wqkv, wqkvT, 1024, 1536);
    transpose_kernel<<<dim3(1024 / 32, 512 / 32), 256, 0, stream>>>(wout, woutT, 512, 1024);
    gemm_qkv_kernel<<<dim3(64, 12), 256, 0, stream>>>(xn, wqkvT, qb, kb, vbT);
    attn_partial_kernel<<<NBH * NSLOT, 256, 0, stream>>>(qb, kb, vbT, part, lpart);
    attn_combine_kernel<<<NBH * 64, 256, 0, stream>>>(part, lpart, aout);
    gemm_out_kernel<<<dim3(64, 8), 256, 0, stream>>>(aout, woutT, out);
}